// Round 13
// baseline (718.484 us; speedup 1.0000x reference)
//
#include <hip/hip_runtime.h>

#define BB 8
#define CC 256
#define TT 4
#define NNv 4096
#define HH 1024
#define LLv (TT*NNv)   // 16384

typedef int int4v __attribute__((ext_vector_type(4)));

// ---- fc1 weights -> 3 signed radix-256 i8 digits, MFMA-fragment-linear ----
// w = (d0*2^16 + d1*2^8 + d2) * 2^-24 exactly (|w|<0.5). Frag block per
// (d, ht64, ko, gg): 64 lanes x 16B; lane = ((c>>4)&3)*16 + (h&15); byte = c&15.
// Mapping verified end-to-end (R3/R10/R11 i8 kernels, absmax 2e-3).
__global__ __launch_bounds__(256) void k_prep1(const float* __restrict__ w,
                                               unsigned char* __restrict__ wd)
{
    int i = blockIdx.x * 256 + threadIdx.x;        // i = h*256 + c
    int h = i >> 8, c = i & 255;
    int w24 = __float2int_rn(w[i] * 16777216.0f);
    int d2 = ((w24 + 128) & 255) - 128;  w24 = (w24 - d2) >> 8;
    int d1 = ((w24 + 128) & 255) - 128;  w24 = (w24 - d1) >> 8;
    int d0 = w24;
    size_t off = ((((size_t)(h >> 6) * 4 + (c >> 6)) * 4 + ((h >> 4) & 3)) << 10)
               + ((c >> 4) & 3) * 256 + (h & 15) * 16 + (c & 15);
    wd[off] = (unsigned char)d0;
    wd[262144 + off] = (unsigned char)d1;
    wd[2 * 262144 + off] = (unsigned char)d2;
}

// ---- fc2 weights -> 2 signed radix-256 i8 digits ----
// w = (d0*2^8 + d1) * 2^-16. Frag block per (d, c64, ko8, kb2, gg): 64 lanes x
// 16B, lane = ((h>>4)&3)*16 + (c&15), byte = h&15. (R3/R10/R11-verified.)
__global__ __launch_bounds__(256) void k_prep2(const float* __restrict__ w,
                                               unsigned char* __restrict__ wd)
{
    int i = blockIdx.x * 256 + threadIdx.x;        // i = c*1024 + h
    int c = i >> 10, h = i & 1023;
    int w16 = __float2int_rn(w[i] * 65536.0f);
    int d1 = ((w16 + 128) & 255) - 128;  w16 = (w16 - d1) >> 8;
    int d0 = w16;
    size_t off = ((((((size_t)(c >> 6) * 8 + (h >> 7)) * 2 + ((h >> 6) & 1)) * 4
                    + ((c >> 4) & 3)) << 10)
                 + ((h >> 4) & 3) * 256 + (c & 15) * 16 + (h & 15));
    wd[off] = (unsigned char)d0;
    wd[262144 + off] = (unsigned char)d1;
}

// ---- bn2 + LIF over T + transpose: x[b][c][t][n] -> s1T[bl][t][n][c] bytes ----
__global__ __launch_bounds__(256) void k_bn2_lif_t(
    const float* __restrict__ x,
    const float* __restrict__ g, const float* __restrict__ be,
    const float* __restrict__ mu, const float* __restrict__ va,
    unsigned char* __restrict__ s1T, int b0)
{
    __shared__ unsigned char ts[TT][64][80];       // [t][c][n], stride 80 (16B-aligned)
    int tx = threadIdx.x;
    int n0 = blockIdx.x * 64;
    int c0 = blockIdx.y * 64;
    int bl = blockIdx.z;
    int b  = b0 + bl;
    int cl = tx >> 2, np = tx & 3;
    int c = c0 + cl;
    float rsq = __fdiv_rn(1.0f, __fsqrt_rn(__fadd_rn(va[c], 1e-5f)));
    float inv = __fmul_rn(g[c], rsq);
    float add = __fsub_rn(be[c], __fmul_rn(mu[c], inv));
    size_t xb = ((size_t)(b * CC + c) * TT) * NNv + n0 + np * 16;
    float v[16];
    #pragma unroll
    for (int i = 0; i < 16; i++) v[i] = 0.0f;
    #pragma unroll
    for (int t = 0; t < TT; t++) {
        float4 p[4];
        #pragma unroll
        for (int k = 0; k < 4; k++) p[k] = *(const float4*)(x + xb + (size_t)t * NNv + 4 * k);
        const float* xp = (const float*)p;
        unsigned int ob[4] = {0, 0, 0, 0};
        #pragma unroll
        for (int i = 0; i < 16; i++) {
            float y = __fadd_rn(__fmul_rn(xp[i], inv), add);
            float vv = __fadd_rn(v[i], __fdiv_rn(__fsub_rn(y, v[i]), 1.5f));
            bool sp = vv >= 1.0f;
            v[i] = sp ? 0.0f : vv;
            if (sp) ob[i >> 2] |= 1u << (8 * (i & 3));
        }
        uint4 pk; pk.x = ob[0]; pk.y = ob[1]; pk.z = ob[2]; pk.w = ob[3];
        *(uint4*)&ts[t][cl][np * 16] = pk;
    }
    __syncthreads();
    int nl = tx >> 2, cp = tx & 3;
    #pragma unroll
    for (int t = 0; t < TT; t++) {
        unsigned int u[4];
        #pragma unroll
        for (int kk = 0; kk < 4; kk++) {
            u[kk] = (unsigned int)ts[t][cp * 16 + kk * 4 + 0][nl]
                  | ((unsigned int)ts[t][cp * 16 + kk * 4 + 1][nl] << 8)
                  | ((unsigned int)ts[t][cp * 16 + kk * 4 + 2][nl] << 16)
                  | ((unsigned int)ts[t][cp * 16 + kk * 4 + 3][nl] << 24);
        }
        uint4 pk; pk.x = u[0]; pk.y = u[1]; pk.z = u[2]; pk.w = u[3];
        *(uint4*)(s1T + ((size_t)(bl * TT + t) * NNv + n0 + nl) * CC + c0 + cp * 16) = pk;
    }
}

// s2T is SEGMENT-MAJOR: addr(bl,l,h) = ((bl*16 + h/64)*LLv + l)*64 + (h&63).
// Every byte of a 64B row-segment is produced by exactly one gemm1 block ->
// full L2 sectors on one XCD -> no HBM write amplification (R11: 2.35x).

// ------- GEMM1 (fc1) i8 3-digit, stage-once + barrier-free ht loop -------
// 512 threads (8 waves: mh x4, wn x2). Stage 32n x 4t x 256c spikes (34.8KB)
// + bn1 param table (12KB) once, ONE barrier; then 16 ht iterations of pure
// {weight-load, ds_read, MFMA, LIF, store} dataflow with zero barriers.
__global__ __launch_bounds__(512, 4) void k_gemm1_lif(
    const unsigned char* __restrict__ w1d,
    const float* __restrict__ b1,
    const float* __restrict__ g1, const float* __restrict__ be1,
    const float* __restrict__ mu1, const float* __restrict__ va1,
    const unsigned char* __restrict__ s1T, unsigned char* __restrict__ s2T)
{
    __shared__ unsigned char Ls[128][272];         // [t*32+n][c], pad 256->272
    __shared__ float Linv[HH], Ladd[HH], Lbias[HH]; // 12KB bn1 params
    const int tx = threadIdx.x;
    const int n0 = blockIdx.x * 32;
    const int bl = blockIdx.z;
    const int lane = tx & 63, w = tx >> 6;         // w 0..7
    const int q = lane >> 4, ln = lane & 15;
    const int mh = (w & 3) * 16;                   // h-offset within 64
    const int wn = (w >> 2) * 16;                  // n-offset within 32

    // bn1 param table (identical arithmetic to previous epilogue)
    #pragma unroll
    for (int rep = 0; rep < 2; rep++) {
        int hh = rep * 512 + tx;
        float rsq = __fdiv_rn(1.0f, __fsqrt_rn(__fadd_rn(va1[hh], 1e-5f)));
        float inv = __fmul_rn(g1[hh], rsq);
        Linv[hh] = inv;
        Ladd[hh] = __fsub_rn(be1[hh], __fmul_rn(mu1[hh], inv));
        Lbias[hh] = b1[hh];
    }
    // stage spikes: 2048 chunks of 16B, 4/thread, coalesced 256B rows
    {
        uint4 st[4];
        #pragma unroll
        for (int i = 0; i < 4; i++) {
            int task = i * 512 + tx;
            int ch = task & 15, row = task >> 4;   // row = t*32+n
            st[i] = *(const uint4*)(s1T + ((size_t)(bl * TT + (row >> 5)) * NNv
                                           + n0 + (row & 31)) * CC + ch * 16);
        }
        #pragma unroll
        for (int i = 0; i < 4; i++) {
            int task = i * 512 + tx;
            int ch = task & 15, row = task >> 4;
            *(uint4*)&Ls[row][ch * 16] = st[i];
        }
    }
    __syncthreads();                               // the ONLY barrier

    for (int ht = 0; ht < 16; ht++) {
        int4v a0[TT], a1[TT], a2[TT];
        #pragma unroll
        for (int t = 0; t < TT; t++) {
            a0[t] = (int4v){0, 0, 0, 0};
            a1[t] = (int4v){0, 0, 0, 0};
            a2[t] = (int4v){0, 0, 0, 0};
        }
        #pragma unroll
        for (int ko = 0; ko < 4; ko++) {
            size_t fb = ((((size_t)ht * 4 + ko) * 4 + (w & 3)) << 10) + lane * 16;
            int4v w0 = *(const int4v*)(w1d + fb);
            int4v w1 = *(const int4v*)(w1d + 262144 + fb);
            int4v w2 = *(const int4v*)(w1d + 2 * 262144 + fb);
            int4v sf[TT];
            #pragma unroll
            for (int t = 0; t < TT; t++)
                sf[t] = *(const int4v*)&Ls[t * 32 + wn + ln][ko * 64 + q * 16];
            #pragma unroll
            for (int t = 0; t < TT; t++) {
                a0[t] = __builtin_amdgcn_mfma_i32_16x16x64_i8(w0, sf[t], a0[t], 0, 0, 0);
                a1[t] = __builtin_amdgcn_mfma_i32_16x16x64_i8(w1, sf[t], a1[t], 0, 0, 0);
                a2[t] = __builtin_amdgcn_mfma_i32_16x16x64_i8(w2, sf[t], a2[t], 0, 0, 0);
            }
        }
        // per-ht epilogue: exact combine -> f32, bias+bn1+LIF, 4B pk stores
        float invr[4], addr_[4], biasr[4];
        #pragma unroll
        for (int r = 0; r < 4; r++) {
            int h = ht * 64 + mh + q * 4 + r;
            invr[r] = Linv[h]; addr_[r] = Ladd[h]; biasr[r] = Lbias[h];
        }
        float v4[4] = {0.f, 0.f, 0.f, 0.f};
        const int nloc = n0 + wn + ln;
        #pragma unroll
        for (int t = 0; t < TT; t++) {
            int4v ci = (((a0[t] << 8) + a1[t]) << 8) + a2[t];
            unsigned int pk = 0;
            #pragma unroll
            for (int r = 0; r < 4; r++) {
                float h1 = __fadd_rn(__fmul_rn((float)ci[r], 5.9604644775390625e-08f),
                                     biasr[r]);    // 2^-24
                float y  = __fadd_rn(__fmul_rn(h1, invr[r]), addr_[r]);
                float vv = __fadd_rn(v4[r], __fdiv_rn(__fsub_rn(y, v4[r]), 1.5f));
                bool sp = vv >= 1.0f;
                v4[r] = sp ? 0.0f : vv;
                if (sp) pk |= (1u << (8 * r));
            }
            *(unsigned int*)(s2T + ((((size_t)(bl * 16 + ht) * LLv + t * NNv + nloc)) << 6)
                             + mh + q * 4) = pk;
        }
    }
}

// ------- GEMM2 (fc2) i8 2-digit, full-K stage (2 barriers total), ct loop -------
// 64l x 256c per block: stage all K=1024 bytes for 64 l-rows (66.6KB, padded
// 1040B rows), then ct(2) x ko(8) x kb(2) pure dataflow, no further barriers.
__global__ __launch_bounds__(256, 2) void k_gemm2(
    const unsigned char* __restrict__ w2d,
    const float* __restrict__ b2c,
    const unsigned char* __restrict__ s2T, float* __restrict__ outp, int b0)
{
    __shared__ unsigned char Ls[64][1040];         // 66,560 B
    const int tx = threadIdx.x;
    const int l0 = blockIdx.x * 64;
    const int bl = blockIdx.z;
    const int b  = b0 + bl;
    const int lane = tx & 63, w = tx >> 6;
    const int q = lane >> 4, ln = lane & 15;
    const int mc = w * 32;                         // c-offset within 128

    // stage: 4096 chunks of 16B, 16/thread in 2 halves (reads are 64B-coalesced
    // groups in the segment-major layout)
    #pragma unroll
    for (int half = 0; half < 2; half++) {
        uint4 st[8];
        #pragma unroll
        for (int i = 0; i < 8; i++) {
            int task = half * 2048 + i * 256 + tx;
            int lr = task >> 6, ch = task & 63;
            st[i] = *(const uint4*)(s2T + ((size_t)(bl * 16 + (ch >> 2)) * LLv
                                           + l0 + lr) * 64 + (ch & 3) * 16);
        }
        #pragma unroll
        for (int i = 0; i < 8; i++) {
            int task = half * 2048 + i * 256 + tx;
            int lr = task >> 6, ch = task & 63;
            *(uint4*)&Ls[lr][ch * 16] = st[i];
        }
    }
    __syncthreads();                               // the ONLY barrier

    for (int ct = 0; ct < 2; ct++) {
        int4v a0[2][4], a1[2][4];                  // [mi][ni] per digit
        #pragma unroll
        for (int mi = 0; mi < 2; mi++)
        #pragma unroll
        for (int ni = 0; ni < 4; ni++) {
            a0[mi][ni] = (int4v){0, 0, 0, 0};
            a1[mi][ni] = (int4v){0, 0, 0, 0};
        }
        #pragma unroll
        for (int ko = 0; ko < 8; ko++)
        #pragma unroll
        for (int kb = 0; kb < 2; kb++) {
            int4v w0[2], w1[2];
            #pragma unroll
            for (int mi = 0; mi < 2; mi++) {
                size_t fb = (((((size_t)(ct * 2 + (w >> 1)) * 8 + ko) * 2 + kb) * 4
                              + (w & 1) * 2 + mi) << 10) + lane * 16;
                w0[mi] = *(const int4v*)(w2d + fb);
                w1[mi] = *(const int4v*)(w2d + 262144 + fb);
            }
            int4v sf[4];
            #pragma unroll
            for (int ni = 0; ni < 4; ni++)
                sf[ni] = *(const int4v*)&Ls[ni * 16 + ln][ko * 128 + kb * 64 + q * 16];
            #pragma unroll
            for (int mi = 0; mi < 2; mi++)
            #pragma unroll
            for (int ni = 0; ni < 4; ni++) {
                a0[mi][ni] = __builtin_amdgcn_mfma_i32_16x16x64_i8(w0[mi], sf[ni], a0[mi][ni], 0, 0, 0);
                a1[mi][ni] = __builtin_amdgcn_mfma_i32_16x16x64_i8(w1[mi], sf[ni], a1[mi][ni], 0, 0, 0);
            }
        }
        #pragma unroll
        for (int mi = 0; mi < 2; mi++)
        #pragma unroll
        for (int ni = 0; ni < 4; ni++) {
            int4v tv = (a0[mi][ni] << 8) + a1[mi][ni];
            #pragma unroll
            for (int r = 0; r < 4; r++) {
                int c = ct * 128 + mc + mi * 16 + q * 4 + r;
                int l = l0 + ni * 16 + ln;
                outp[((size_t)b * CC + c) * LLv + l] =
                    __fadd_rn(__fmul_rn((float)tv[r], 1.52587890625e-05f), b2c[c]); // 2^-16
            }
        }
    }
}

extern "C" void kernel_launch(void* const* d_in, const int* in_sizes, int n_in,
                              void* d_out, int out_size, void* d_ws, size_t ws_size,
                              hipStream_t stream) {
    const float* x    = (const float*)d_in[0];
    const float* fc1w = (const float*)d_in[1];
    const float* fc1b = (const float*)d_in[2];
    const float* fc2w = (const float*)d_in[3];
    const float* fc2b = (const float*)d_in[4];
    const float* g1   = (const float*)d_in[5];
    const float* be1  = (const float*)d_in[6];
    const float* mu1  = (const float*)d_in[7];
    const float* va1  = (const float*)d_in[8];
    const float* g2   = (const float*)d_in[9];
    const float* be2  = (const float*)d_in[10];
    const float* mu2  = (const float*)d_in[11];
    const float* va2  = (const float*)d_in[12];

    // Workspace layout (ws_size-adaptive; NEVER exceed ws_size — overflow
    // clobbers adjacent input allocations and corrupts x on later calls):
    //   w1d: 3*262144 i8 digits (768 KB)
    //   w2d: 2*262144 i8 digits (512 KB)
    //   s1T: (full? 8 : 1) * 4 MB      bn2+LIF spike bytes [b][t][n][c]
    //   s2T: nbc * 16.78 MB            layer-1 spikes, SEGMENT-MAJOR
    const size_t WB  = (size_t)3 * 262144 + (size_t)2 * 262144;          // 1,310,720
    const size_t S1B = (size_t)TT * NNv * CC;                            // 4,194,304 per b
    const size_t S2B = (size_t)LLv * HH;                                 // 16,777,216 per b

    int nbc;          // batch elements per gemm1/gemm2 chunk
    bool full_s1;     // s1T holds all 8 batches (bn2 runs once)?
    if      (ws_size >= WB + 8 * S1B + 8 * S2B) { nbc = 8; full_s1 = true;  }
    else if (ws_size >= WB + 8 * S1B + 4 * S2B) { nbc = 4; full_s1 = true;  }
    else if (ws_size >= WB + 8 * S1B + 2 * S2B) { nbc = 2; full_s1 = true;  }
    else if (ws_size >= WB + 8 * S1B + 1 * S2B) { nbc = 1; full_s1 = true;  }
    else                                        { nbc = 1; full_s1 = false; }

    unsigned char* w1d = (unsigned char*)d_ws;
    unsigned char* w2d = w1d + (size_t)3 * 262144;
    unsigned char* s1T = w2d + (size_t)2 * 262144;
    unsigned char* s2T = s1T + (full_s1 ? (size_t)8 * S1B : S1B);
    float* outp = (float*)d_out;

    hipLaunchKernelGGL(k_prep1, dim3(1024), dim3(256), 0, stream, fc1w, w1d);
    hipLaunchKernelGGL(k_prep2, dim3(1024), dim3(256), 0, stream, fc2w, w2d);

    if (full_s1) {
        hipLaunchKernelGGL(k_bn2_lif_t, dim3(NNv / 64, CC / 64, BB), dim3(256), 0, stream,
                           x, g2, be2, mu2, va2, s1T, 0);
        for (int b0 = 0; b0 < BB; b0 += nbc) {
            hipLaunchKernelGGL(k_gemm1_lif, dim3(NNv / 32, 1, nbc), dim3(512), 0, stream,
                               w1d, fc1b, g1, be1, mu1, va1, s1T + (size_t)b0 * S1B, s2T);
            hipLaunchKernelGGL(k_gemm2, dim3(LLv / 64, 1, nbc), dim3(256), 0, stream,
                               w2d, fc2b, s2T, outp, b0);
        }
    } else {
        for (int b0 = 0; b0 < BB; ++b0) {
            hipLaunchKernelGGL(k_bn2_lif_t, dim3(NNv / 64, CC / 64, 1), dim3(256), 0, stream,
                               x, g2, be2, mu2, va2, s1T, b0);
            hipLaunchKernelGGL(k_gemm1_lif, dim3(NNv / 32, 1, 1), dim3(512), 0, stream,
                               w1d, fc1b, g1, be1, mu1, va1, s1T, s2T);
            hipLaunchKernelGGL(k_gemm2, dim3(LLv / 64, 1, 1), dim3(256), 0, stream,
                               w2d, fc2b, s2T, outp, b0);
        }
    }
}